// Round 8
// baseline (448.909 us; speedup 1.0000x reference)
//
#include <hip/hip_runtime.h>
#include <hip/hip_bf16.h>
#include <cstdint>
#include <cstddef>

typedef __bf16 bf16_t;
typedef bf16_t bf16x8 __attribute__((ext_vector_type(8)));
typedef float floatx4 __attribute__((ext_vector_type(4)));

static constexpr int B_ = 8192;   // batch
static constexpr int H_ = 1024;   // hidden
static constexpr int G4 = 4096;   // 4*H
static constexpr int K_ = 1024;   // input size == hidden size

// ---- async global->LDS, 16B per lane. HW semantics: lane's dest =
// WAVE-UNIFORM base + lane*16; global src is per-lane.
__device__ inline void async16(const void* g, void* l) {
  auto l3 = (__attribute__((address_space(3))) void*)(uint32_t)(uintptr_t)l;
  __builtin_amdgcn_global_load_lds(
      (__attribute__((address_space(1))) void*)(uintptr_t)g, l3, 16, 0, 0);
}

// ---------------- fused prep: casts + weight permute, ONE launch ------------
__global__ __launch_bounds__(256) void prep_all(
    const float* __restrict__ input, const float* __restrict__ hx,
    const float* __restrict__ wih, const float* __restrict__ whh,
    bf16_t* __restrict__ Abf, bf16_t* __restrict__ Hbf,
    bf16_t* __restrict__ Wib, bf16_t* __restrict__ Whb) {
  const int bid = blockIdx.x;
  if (bid < 4096) {
    const int nt = B_ * K_ / 16;                // 512K per tensor
    int gid = bid * 256 + threadIdx.x;          // [0, 1M)
    const float* src; bf16_t* dst; int idx;
    if (gid < nt) { src = input; dst = Abf; idx = gid; }
    else          { src = hx;    dst = Hbf; idx = gid - nt; }
    const float4* s4 = (const float4*)src + (size_t)idx * 4;
    const float4 v0 = s4[0], v1 = s4[1], v2 = s4[2], v3 = s4[3];
    bf16x8 o0, o1;
    o0[0] = (bf16_t)v0.x; o0[1] = (bf16_t)v0.y; o0[2] = (bf16_t)v0.z; o0[3] = (bf16_t)v0.w;
    o0[4] = (bf16_t)v1.x; o0[5] = (bf16_t)v1.y; o0[6] = (bf16_t)v1.z; o0[7] = (bf16_t)v1.w;
    o1[0] = (bf16_t)v2.x; o1[1] = (bf16_t)v2.y; o1[2] = (bf16_t)v2.z; o1[3] = (bf16_t)v2.w;
    o1[4] = (bf16_t)v3.x; o1[5] = (bf16_t)v3.y; o1[6] = (bf16_t)v3.z; o1[7] = (bf16_t)v3.w;
    ((bf16x8*)dst)[(size_t)idx * 2]     = o0;
    ((bf16x8*)dst)[(size_t)idx * 2 + 1] = o1;
  } else {
    const int r  = bid - 4096;                  // [0, 4096): row-pair index
    const int rr = r * 2 + (threadIdx.x >> 7);  // global out row [0, 8192)
    const int rp = rr & 4095;                   // row within matrix
    const float* src = (rr < 4096) ? wih : whh;
    bf16_t*      dst = (rr < 4096) ? Wib : Whb;
    const int h = rp >> 2, g = rp & 3;
    const int rin = g * 1024 + h;
    const int c = (threadIdx.x & 127) * 8;
    const float4 v0 = *(const float4*)(src + (size_t)rin * K_ + c);
    const float4 v1 = *(const float4*)(src + (size_t)rin * K_ + c + 4);
    bf16x8 o;
    o[0] = (bf16_t)v0.x; o[1] = (bf16_t)v0.y; o[2] = (bf16_t)v0.z; o[3] = (bf16_t)v0.w;
    o[4] = (bf16_t)v1.x; o[5] = (bf16_t)v1.y; o[6] = (bf16_t)v1.z; o[7] = (bf16_t)v1.w;
    *(bf16x8*)(dst + (size_t)rp * K_ + c) = o;
  }
}

// ---------------- dual GEMM: C = A * W^T (both K-major), bf16 in/out --------
// R6 version (best stable: 141 us, WRITE exactly 128 MiB). 256x256 8-phase
// template, BK=64, 8 waves 2Mx4N, counted vmcnt(4), setprio, XOR-swizzled
// LDS (linear gload_lds dest + inverse-swizzled global src, rule #21),
// bijective XCD swizzle.
#define FENCE() asm volatile("" ::: "memory")
#define BARRIER() do { FENCE(); __builtin_amdgcn_s_barrier(); FENCE(); } while (0)

__global__ __launch_bounds__(512, 2) void gemm_bt_dual8(
    const bf16_t* __restrict__ A0, const bf16_t* __restrict__ A1,
    const bf16_t* __restrict__ W0, const bf16_t* __restrict__ W1,
    bf16_t* __restrict__ C0, bf16_t* __restrict__ C1) {
  constexpr int N = G4, K = K_, NT = K_ / 64;

  __shared__ bf16_t ldsA[2][16384];   // [buf][256 rows x 64 cols]
  __shared__ bf16_t ldsB[2][16384];

  // bijective XCD swizzle of flat block id (x fastest in dispatch order)
  const int flatb = blockIdx.x + (blockIdx.y << 4) + (blockIdx.z << 9);
  const int swzb  = (flatb & 7) * 128 + (flatb >> 3);
  const int bz = swzb >> 9;
  const int by = (swzb >> 4) & 31;
  const int bx = swzb & 15;

  const bf16_t* A = bz ? A1 : A0;
  const bf16_t* W = bz ? W1 : W0;
  bf16_t*       C = bz ? C1 : C0;

  const int tid  = threadIdx.x;
  const int lane = tid & 63;
  const int w    = tid >> 6;          // wave 0..7
  const int wm   = w >> 2, wn = w & 3;
  const int lrow = lane & 15, quad = lane >> 4;
  const int e    = lrow & 7;

  const int m0 = by * 256;
  const int n0 = bx * 256;

  // staging: thread t covers LDS 16B slot t of an 8KB sub-half (64 rows x 64
  // cols). row = t>>3, slot = t&7; global source chunk = slot ^ (row&7).
  const int srow   = tid >> 3;
  const int schunk = (tid & 7) ^ (srow & 7);
  const bf16_t* gA = A + (size_t)(m0 + srow) * K + schunk * 8;
  const bf16_t* gB = W + (size_t)(n0 + srow) * K + schunk * 8;
  const int wslot = w * 512;          // wave-uniform elem offset in sub-half

  // fragment read bases (elements), swizzled chunk = (ks*4+quad) ^ e
  const int aBase = (wm * 128 + lrow) * 64 + (quad ^ e) * 8;
  const int bBase = (wn * 64 + lrow) * 64 + (quad ^ e) * 8;

  floatx4 acc[8][4] = {};
  bf16x8 aF[4][2];
  bf16x8 bF[2][2][2];

#define STG_A(p, half, kt) do {                                          \
    bf16_t* _l = &ldsA[p][(half) * 8192 + wslot];                        \
    async16(gA + (size_t)((half) * 128) * K + (kt) * 64, _l);            \
    async16(gA + (size_t)((half) * 128 + 64) * K + (kt) * 64, _l + 4096); \
  } while (0)
#define STG_B(p, half, kt) do {                                          \
    bf16_t* _l = &ldsB[p][(half) * 8192 + wslot];                        \
    async16(gB + (size_t)((half) * 128) * K + (kt) * 64, _l);            \
    async16(gB + (size_t)((half) * 128 + 64) * K + (kt) * 64, _l + 4096); \
  } while (0)

#define LD_A(p, qm) do { _Pragma("unroll")                               \
    for (int i2 = 0; i2 < 4; ++i2) {                                     \
      const int o = aBase + (qm) * 4096 + i2 * 1024;                     \
      aF[i2][0] = *(const bf16x8*)&ldsA[p][o];                           \
      aF[i2][1] = *(const bf16x8*)&ldsA[p][o ^ 32];                      \
    } } while (0)
#define LD_B(p, qn) do { _Pragma("unroll")                               \
    for (int j2 = 0; j2 < 2; ++j2) {                                     \
      const int o = bBase + (qn) * 2048 + j2 * 1024;                     \
      bF[qn][j2][0] = *(const bf16x8*)&ldsB[p][o];                       \
      bF[qn][j2][1] = *(const bf16x8*)&ldsB[p][o ^ 32];                  \
    } } while (0)
#define MFMA_Q(qm, qn) do { _Pragma("unroll")                            \
    for (int i2 = 0; i2 < 4; ++i2) { _Pragma("unroll")                   \
      for (int j2 = 0; j2 < 2; ++j2) {                                   \
        floatx4& c = acc[(qm) * 4 + i2][(qn) * 2 + j2];                  \
        c = __builtin_amdgcn_mfma_f32_16x16x32_bf16(aF[i2][0], bF[qn][j2][0], c, 0, 0, 0); \
        c = __builtin_amdgcn_mfma_f32_16x16x32_bf16(aF[i2][1], bF[qn][j2][1], c, 0, 0, 0); \
      } } } while (0)

  // prologue: tile0 complete + tile1 B-halves; wait tile0 (leave tile1.B in flight)
  STG_B(0, 0, 0); STG_B(0, 1, 0);
  STG_A(0, 0, 0); STG_A(0, 1, 0);
  STG_B(1, 0, 1); STG_B(1, 1, 1);
  asm volatile("s_waitcnt vmcnt(4)" ::: "memory");
  BARRIER();

#pragma unroll 2
  for (int t = 0; t < NT; ++t) {
    const int p = t & 1, q = p ^ 1;
    const int t1 = (t + 1) & (NT - 1), t2 = (t + 2) & (NT - 1);

    // ---- phase 1: quadrant (0,0)
    LD_A(p, 0); LD_B(p, 0);
    STG_A(q, 0, t1);
    BARRIER();
    asm volatile("s_waitcnt lgkmcnt(0)" ::: "memory");
    __builtin_amdgcn_sched_barrier(0);
    __builtin_amdgcn_s_setprio(1); MFMA_Q(0, 0); __builtin_amdgcn_s_setprio(0);
    BARRIER();

    // ---- phase 2: quadrant (0,1)
    LD_B(p, 1);
    STG_A(q, 1, t1);
    BARRIER();
    asm volatile("s_waitcnt lgkmcnt(0)" ::: "memory");
    __builtin_amdgcn_sched_barrier(0);
    __builtin_amdgcn_s_setprio(1); MFMA_Q(0, 1); __builtin_amdgcn_s_setprio(0);
    BARRIER();

    // ---- phase 3: quadrant (1,0)
    LD_A(p, 1);
    STG_B(p, 0, t2);
    BARRIER();
    asm volatile("s_waitcnt lgkmcnt(0)" ::: "memory");
    __builtin_amdgcn_sched_barrier(0);
    __builtin_amdgcn_s_setprio(1); MFMA_Q(1, 0); __builtin_amdgcn_s_setprio(0);
    BARRIER();

    // ---- phase 4: quadrant (1,1); counted vmcnt AFTER the MFMA cluster
    STG_B(p, 1, t2);
    BARRIER();
    __builtin_amdgcn_s_setprio(1); MFMA_Q(1, 1); __builtin_amdgcn_s_setprio(0);
    asm volatile("s_waitcnt vmcnt(4)" ::: "memory");
    BARRIER();
  }

  // C/D layout (m89-verified): col(n)=lane&15, row(m)=quad*4+reg
#pragma unroll
  for (int i = 0; i < 8; ++i) {
    const int mbase = m0 + wm * 128 + i * 16 + quad * 4;
#pragma unroll
    for (int j = 0; j < 4; ++j) {
      const int n = n0 + wn * 64 + j * 16 + lrow;
#pragma unroll
      for (int r = 0; r < 4; ++r)
        C[(size_t)(mbase + r) * N + n] = (bf16_t)acc[i][j][r];
    }
  }
#undef STG_A
#undef STG_B
#undef LD_A
#undef LD_B
#undef MFMA_Q
}

// ---------------- fused epilogue: 4 ROWS PER WAVE ---------------------------
// 512 blocks x 4 waves; each wave owns 4 batch rows. LN params are loaded
// ONCE per c-chunk and applied to all 4 rows -> param L2 traffic /4
// (590 MB -> 147 MB, the measured dominant stream of the 73us epi_wave2).
// Gates are read twice (stats pass + gate pass); second read is L3-resident
// (gates 128 MB < 256 MB L3). ov kept bf16-packed to bound VGPRs.
// All reductions are 64-lane __shfl_xor butterflies; no LDS, no barriers.
__device__ inline float sigmoid_f(float x) { return 1.0f / (1.0f + __expf(-x)); }
__device__ inline float tanh_f(float x) {
  float e = __expf(2.0f * x);
  return 1.0f - 2.0f / (e + 1.0f);   // safe at +/-inf
}

__global__ __launch_bounds__(256) void ln_lstm_epi4(
    const bf16_t* __restrict__ IG, const bf16_t* __restrict__ HG,
    const float* __restrict__ cx,
    const float* __restrict__ wi, const float* __restrict__ bi,
    const float* __restrict__ wh, const float* __restrict__ bh,
    const float* __restrict__ wc, const float* __restrict__ bc,
    float* __restrict__ hy_out, float* __restrict__ cy_out) {
  const int l  = threadIdx.x & 63;
  const int wv = threadIdx.x >> 6;            // wave 0..3
  const int b0 = blockIdx.x * 16 + wv * 4;    // rows b0..b0+3

  // ---- pass 1: gate-LN stats for 4 rows (gates streamed, not kept)
  float si[4] = {}, qi[4] = {}, sh[4] = {}, qh[4] = {};
#pragma unroll
  for (int r = 0; r < 4; ++r) {
    const bf16_t* igp = IG + (size_t)(b0 + r) * 4096;
    const bf16_t* hgp = HG + (size_t)(b0 + r) * 4096;
#pragma unroll
    for (int c = 0; c < 4; ++c) {
      const int n0 = c * 1024 + l * 16;
      const bf16x8 a0 = *(const bf16x8*)(igp + n0);
      const bf16x8 a1 = *(const bf16x8*)(igp + n0 + 8);
      const bf16x8 d0 = *(const bf16x8*)(hgp + n0);
      const bf16x8 d1 = *(const bf16x8*)(hgp + n0 + 8);
#pragma unroll
      for (int e = 0; e < 8; ++e) {
        const float x0 = (float)a0[e], x1 = (float)a1[e];
        const float y0 = (float)d0[e], y1 = (float)d1[e];
        si[r] += x0 + x1; qi[r] = fmaf(x0, x0, fmaf(x1, x1, qi[r]));
        sh[r] += y0 + y1; qh[r] = fmaf(y0, y0, fmaf(y1, y1, qh[r]));
      }
    }
  }
#pragma unroll
  for (int off = 1; off < 64; off <<= 1)
#pragma unroll
    for (int r = 0; r < 4; ++r) {
      si[r] += __shfl_xor(si[r], off); qi[r] += __shfl_xor(qi[r], off);
      sh[r] += __shfl_xor(sh[r], off); qh[r] += __shfl_xor(qh[r], off);
    }
  const float invN = 1.0f / 4096.0f;
  float mui[4], rsi[4], muh[4], rsh[4];
#pragma unroll
  for (int r = 0; r < 4; ++r) {
    mui[r] = si[r] * invN; muh[r] = sh[r] * invN;
    rsi[r] = rsqrtf(fmaxf(qi[r] * invN - mui[r] * mui[r], 0.0f) + 1e-5f);
    rsh[r] = rsqrtf(fmaxf(qh[r] * invN - muh[r] * muh[r], 0.0f) + 1e-5f);
  }

  // ---- pass 2: params once per c-chunk, applied to 4 rows
  float  cvv[4][16];
  bf16x8 ovv[4][2];                    // ov packed bf16 (err ~0.2% << absmax)
  float  scc[4] = {}, qcc[4] = {};
#pragma unroll
  for (int c = 0; c < 4; ++c) {
    const int h0 = c * 256 + l * 4;
    float4 wiv[4], biv[4], whv[4], bhv[4];
#pragma unroll
    for (int g = 0; g < 4; ++g) {
      wiv[g] = *(const float4*)(wi + g * 1024 + h0);
      biv[g] = *(const float4*)(bi + g * 1024 + h0);
      whv[g] = *(const float4*)(wh + g * 1024 + h0);
      bhv[g] = *(const float4*)(bh + g * 1024 + h0);
    }
#pragma unroll
    for (int r = 0; r < 4; ++r) {
      const bf16_t* igp = IG + (size_t)(b0 + r) * 4096;
      const bf16_t* hgp = HG + (size_t)(b0 + r) * 4096;
      const int n0 = c * 1024 + l * 16;
      const bf16x8 a0 = *(const bf16x8*)(igp + n0);
      const bf16x8 a1 = *(const bf16x8*)(igp + n0 + 8);
      const bf16x8 d0 = *(const bf16x8*)(hgp + n0);
      const bf16x8 d1 = *(const bf16x8*)(hgp + n0 + 8);
      const float4 c4 = *(const float4*)(cx + (size_t)(b0 + r) * 1024 + h0);
#pragma unroll
      for (int kk = 0; kk < 4; ++kk) {
        float G[4];
#pragma unroll
        for (int g = 0; g < 4; ++g) {
          const int idx = kk * 4 + g;
          const float gi = (idx < 8) ? (float)a0[idx] : (float)a1[idx - 8];
          const float gh = (idx < 8) ? (float)d0[idx] : (float)d1[idx - 8];
          G[g] = (gi - mui[r]) * rsi[r] * ((const float*)&wiv[g])[kk] +
                 ((const float*)&biv[g])[kk] +
                 (gh - muh[r]) * rsh[r] * ((const float*)&whv[g])[kk] +
                 ((const float*)&bhv[g])[kk];
        }
        const float in_g = sigmoid_f(G[0]);
        const float fo_g = sigmoid_f(G[1]);
        const float ce_g = tanh_f(G[2]);
        const float o_g  = sigmoid_f(G[3]);
        const float cc = fo_g * ((const float*)&c4)[kk] + in_g * ce_g;
        const int idx = c * 4 + kk;
        cvv[r][idx] = cc;
        ovv[r][idx >> 3][idx & 7] = (bf16_t)o_g;
        scc[r] += cc; qcc[r] = fmaf(cc, cc, qcc[r]);
      }
    }
  }
#pragma unroll
  for (int off = 1; off < 64; off <<= 1)
#pragma unroll
    for (int r = 0; r < 4; ++r) {
      scc[r] += __shfl_xor(scc[r], off); qcc[r] += __shfl_xor(qcc[r], off);
    }
  const float invH = 1.0f / 1024.0f;
  float muc[4], rsc[4];
#pragma unroll
  for (int r = 0; r < 4; ++r) {
    muc[r] = scc[r] * invH;
    rsc[r] = rsqrtf(fmaxf(qcc[r] * invH - muc[r] * muc[r], 0.0f) + 1e-5f);
  }

  // ---- pass 3: c-LN + outputs (wc/bc loaded once per c-chunk)
#pragma unroll
  for (int c = 0; c < 4; ++c) {
    const int h0 = c * 256 + l * 4;
    const float4 wc4 = *(const float4*)(wc + h0);
    const float4 bc4 = *(const float4*)(bc + h0);
#pragma unroll
    for (int r = 0; r < 4; ++r) {
      float4 cyv, hyv;
#pragma unroll
      for (int kk = 0; kk < 4; ++kk) {
        const int idx = c * 4 + kk;
        const float cyn = (cvv[r][idx] - muc[r]) * rsc[r] *
                          ((const float*)&wc4)[kk] + ((const float*)&bc4)[kk];
        ((float*)&cyv)[kk] = cyn;
        ((float*)&hyv)[kk] = (float)ovv[r][idx >> 3][idx & 7] * tanh_f(cyn);
      }
      *(float4*)(cy_out + (size_t)(b0 + r) * 1024 + h0) = cyv;
      *(float4*)(hy_out + (size_t)(b0 + r) * 1024 + h0) = hyv;
    }
  }
}

extern "C" void kernel_launch(void* const* d_in, const int* in_sizes, int n_in,
                              void* d_out, int out_size, void* d_ws, size_t ws_size,
                              hipStream_t stream) {
  const float* input  = (const float*)d_in[0];
  const float* hx     = (const float*)d_in[1];
  const float* cx     = (const float*)d_in[2];
  const float* w_ih   = (const float*)d_in[3];
  const float* w_hh   = (const float*)d_in[4];
  const float* ln_i_w = (const float*)d_in[5];
  const float* ln_i_b = (const float*)d_in[6];
  const float* ln_h_w = (const float*)d_in[7];
  const float* ln_h_b = (const float*)d_in[8];
  const float* ln_c_w = (const float*)d_in[9];
  const float* ln_c_b = (const float*)d_in[10];

  float* out = (float*)d_out;
  float* hy = out;
  float* cy = out + (size_t)B_ * H_;

  // workspace (bf16): A 16MB | H 16MB | Wih 8MB | Whh 8MB | IG 64MB | HG 64MB
  bf16_t* Abf = (bf16_t*)d_ws;
  bf16_t* Hbf = Abf + (size_t)B_ * K_;
  bf16_t* Wib = Hbf + (size_t)B_ * K_;
  bf16_t* Whb = Wib + (size_t)G4 * K_;
  bf16_t* IG  = Whb + (size_t)G4 * K_;
  bf16_t* HG  = IG + (size_t)B_ * G4;

  prep_all<<<8192, 256, 0, stream>>>(input, hx, w_ih, w_hh, Abf, Hbf, Wib, Whb);

  gemm_bt_dual8<<<dim3(16, 32, 2), 512, 0, stream>>>(Abf, Hbf, Wib, Whb, IG, HG);

  ln_lstm_epi4<<<512, 256, 0, stream>>>(IG, HG, cx, ln_i_w, ln_i_b,
                                        ln_h_w, ln_h_b, ln_c_w, ln_c_b, hy, cy);
}

// Round 9
// 374.924 us; speedup vs baseline: 1.1973x; 1.1973x over previous
//
#include <hip/hip_runtime.h>
#include <hip/hip_bf16.h>
#include <cstdint>
#include <cstddef>

typedef __bf16 bf16_t;
typedef bf16_t bf16x8 __attribute__((ext_vector_type(8)));
typedef float floatx4 __attribute__((ext_vector_type(4)));

static constexpr int B_ = 8192;   // batch
static constexpr int H_ = 1024;   // hidden
static constexpr int G4 = 4096;   // 4*H
static constexpr int K_ = 1024;   // input size == hidden size

// ---- async global->LDS, 16B per lane. HW semantics: lane's dest =
// WAVE-UNIFORM base + lane*16; global src is per-lane.
__device__ inline void async16(const void* g, void* l) {
  auto l3 = (__attribute__((address_space(3))) void*)(uint32_t)(uintptr_t)l;
  __builtin_amdgcn_global_load_lds(
      (__attribute__((address_space(1))) void*)(uintptr_t)g, l3, 16, 0, 0);
}

// ---------------- fused prep: casts + weight permute, ONE launch ------------
// blocks [0,2048):    input+hx fp32 -> bf16, 32 elems/thread (128B contig read)
// blocks [2048,4096): weight rows fp32 -> bf16 with gate-interleave perm,
//                     4 rows/block, 64 lanes x 16 elems per row
//                     (out row r' = h*4+g  <-  in row r = g*1024+h)
__global__ __launch_bounds__(256) void prep_all2(
    const float* __restrict__ input, const float* __restrict__ hx,
    const float* __restrict__ wih, const float* __restrict__ whh,
    bf16_t* __restrict__ Abf, bf16_t* __restrict__ Hbf,
    bf16_t* __restrict__ Wib, bf16_t* __restrict__ Whb) {
  const int bid = blockIdx.x;
  if (bid < 2048) {
    // 2M chunks of 8 floats total (1M input, 1M hx); 4 chunks/thread.
    const int nt = B_ * K_ / 8;                 // 1M chunks per tensor
    const int c0 = (bid * 256 + threadIdx.x) * 4;  // first chunk [0, 2M)
    const float* src; bf16_t* dst; int idx;
    if (c0 < nt) { src = input; dst = Abf; idx = c0; }
    else         { src = hx;    dst = Hbf; idx = c0 - nt; }
    const float4* s4 = (const float4*)src + (size_t)idx * 2;
#pragma unroll
    for (int c = 0; c < 4; ++c) {
      const float4 v0 = s4[c * 2], v1 = s4[c * 2 + 1];
      bf16x8 o;
      o[0] = (bf16_t)v0.x; o[1] = (bf16_t)v0.y; o[2] = (bf16_t)v0.z; o[3] = (bf16_t)v0.w;
      o[4] = (bf16_t)v1.x; o[5] = (bf16_t)v1.y; o[6] = (bf16_t)v1.z; o[7] = (bf16_t)v1.w;
      ((bf16x8*)dst)[idx + c] = o;
    }
  } else {
    const int rb = (bid - 2048) * 4;            // first output row of block
    const int rr = rb + (threadIdx.x >> 6);     // global out row [0, 8192)
    const int rp = rr & 4095;                   // row within matrix
    const float* src = (rr < 4096) ? wih : whh;
    bf16_t*      dst = (rr < 4096) ? Wib : Whb;
    const int h = rp >> 2, g = rp & 3;
    const int rin = g * 1024 + h;
    const int c = (threadIdx.x & 63) * 16;
    const float4* s4 = (const float4*)(src + (size_t)rin * K_ + c);
    const float4 v0 = s4[0], v1 = s4[1], v2 = s4[2], v3 = s4[3];
    bf16x8 o0, o1;
    o0[0] = (bf16_t)v0.x; o0[1] = (bf16_t)v0.y; o0[2] = (bf16_t)v0.z; o0[3] = (bf16_t)v0.w;
    o0[4] = (bf16_t)v1.x; o0[5] = (bf16_t)v1.y; o0[6] = (bf16_t)v1.z; o0[7] = (bf16_t)v1.w;
    o1[0] = (bf16_t)v2.x; o1[1] = (bf16_t)v2.y; o1[2] = (bf16_t)v2.z; o1[3] = (bf16_t)v2.w;
    o1[4] = (bf16_t)v3.x; o1[5] = (bf16_t)v3.y; o1[6] = (bf16_t)v3.z; o1[7] = (bf16_t)v3.w;
    *(bf16x8*)(dst + (size_t)rp * K_ + c)     = o0;
    *(bf16x8*)(dst + (size_t)rp * K_ + c + 8) = o1;
  }
}

// ---------------- dual GEMM: C = A * W^T (both K-major), bf16 in/out --------
// R6 version (best stable: 141 us). 256x256 8-phase template, BK=64, 8 waves
// 2Mx4N, counted vmcnt(4), setprio, XOR-swizzled LDS (linear gload_lds dest
// + inverse-swizzled global src, rule #21), bijective XCD swizzle.
#define FENCE() asm volatile("" ::: "memory")
#define BARRIER() do { FENCE(); __builtin_amdgcn_s_barrier(); FENCE(); } while (0)

__global__ __launch_bounds__(512, 2) void gemm_bt_dual8(
    const bf16_t* __restrict__ A0, const bf16_t* __restrict__ A1,
    const bf16_t* __restrict__ W0, const bf16_t* __restrict__ W1,
    bf16_t* __restrict__ C0, bf16_t* __restrict__ C1) {
  constexpr int N = G4, K = K_, NT = K_ / 64;

  __shared__ bf16_t ldsA[2][16384];   // [buf][256 rows x 64 cols]
  __shared__ bf16_t ldsB[2][16384];

  // bijective XCD swizzle of flat block id (x fastest in dispatch order)
  const int flatb = blockIdx.x + (blockIdx.y << 4) + (blockIdx.z << 9);
  const int swzb  = (flatb & 7) * 128 + (flatb >> 3);
  const int bz = swzb >> 9;
  const int by = (swzb >> 4) & 31;
  const int bx = swzb & 15;

  const bf16_t* A = bz ? A1 : A0;
  const bf16_t* W = bz ? W1 : W0;
  bf16_t*       C = bz ? C1 : C0;

  const int tid  = threadIdx.x;
  const int lane = tid & 63;
  const int w    = tid >> 6;          // wave 0..7
  const int wm   = w >> 2, wn = w & 3;
  const int lrow = lane & 15, quad = lane >> 4;
  const int e    = lrow & 7;

  const int m0 = by * 256;
  const int n0 = bx * 256;

  // staging: thread t covers LDS 16B slot t of an 8KB sub-half (64 rows x 64
  // cols). row = t>>3, slot = t&7; global source chunk = slot ^ (row&7).
  const int srow   = tid >> 3;
  const int schunk = (tid & 7) ^ (srow & 7);
  const bf16_t* gA = A + (size_t)(m0 + srow) * K + schunk * 8;
  const bf16_t* gB = W + (size_t)(n0 + srow) * K + schunk * 8;
  const int wslot = w * 512;          // wave-uniform elem offset in sub-half

  // fragment read bases (elements), swizzled chunk = (ks*4+quad) ^ e
  const int aBase = (wm * 128 + lrow) * 64 + (quad ^ e) * 8;
  const int bBase = (wn * 64 + lrow) * 64 + (quad ^ e) * 8;

  floatx4 acc[8][4] = {};
  bf16x8 aF[4][2];
  bf16x8 bF[2][2][2];

#define STG_A(p, half, kt) do {                                          \
    bf16_t* _l = &ldsA[p][(half) * 8192 + wslot];                        \
    async16(gA + (size_t)((half) * 128) * K + (kt) * 64, _l);            \
    async16(gA + (size_t)((half) * 128 + 64) * K + (kt) * 64, _l + 4096); \
  } while (0)
#define STG_B(p, half, kt) do {                                          \
    bf16_t* _l = &ldsB[p][(half) * 8192 + wslot];                        \
    async16(gB + (size_t)((half) * 128) * K + (kt) * 64, _l);            \
    async16(gB + (size_t)((half) * 128 + 64) * K + (kt) * 64, _l + 4096); \
  } while (0)

#define LD_A(p, qm) do { _Pragma("unroll")                               \
    for (int i2 = 0; i2 < 4; ++i2) {                                     \
      const int o = aBase + (qm) * 4096 + i2 * 1024;                     \
      aF[i2][0] = *(const bf16x8*)&ldsA[p][o];                           \
      aF[i2][1] = *(const bf16x8*)&ldsA[p][o ^ 32];                      \
    } } while (0)
#define LD_B(p, qn) do { _Pragma("unroll")                               \
    for (int j2 = 0; j2 < 2; ++j2) {                                     \
      const int o = bBase + (qn) * 2048 + j2 * 1024;                     \
      bF[qn][j2][0] = *(const bf16x8*)&ldsB[p][o];                       \
      bF[qn][j2][1] = *(const bf16x8*)&ldsB[p][o ^ 32];                  \
    } } while (0)
#define MFMA_Q(qm, qn) do { _Pragma("unroll")                            \
    for (int i2 = 0; i2 < 4; ++i2) { _Pragma("unroll")                   \
      for (int j2 = 0; j2 < 2; ++j2) {                                   \
        floatx4& c = acc[(qm) * 4 + i2][(qn) * 2 + j2];                  \
        c = __builtin_amdgcn_mfma_f32_16x16x32_bf16(aF[i2][0], bF[qn][j2][0], c, 0, 0, 0); \
        c = __builtin_amdgcn_mfma_f32_16x16x32_bf16(aF[i2][1], bF[qn][j2][1], c, 0, 0, 0); \
      } } } while (0)

  // prologue: tile0 complete + tile1 B-halves; wait tile0 (leave tile1.B in flight)
  STG_B(0, 0, 0); STG_B(0, 1, 0);
  STG_A(0, 0, 0); STG_A(0, 1, 0);
  STG_B(1, 0, 1); STG_B(1, 1, 1);
  asm volatile("s_waitcnt vmcnt(4)" ::: "memory");
  BARRIER();

#pragma unroll 2
  for (int t = 0; t < NT; ++t) {
    const int p = t & 1, q = p ^ 1;
    const int t1 = (t + 1) & (NT - 1), t2 = (t + 2) & (NT - 1);

    // ---- phase 1: quadrant (0,0)
    LD_A(p, 0); LD_B(p, 0);
    STG_A(q, 0, t1);
    BARRIER();
    asm volatile("s_waitcnt lgkmcnt(0)" ::: "memory");
    __builtin_amdgcn_sched_barrier(0);
    __builtin_amdgcn_s_setprio(1); MFMA_Q(0, 0); __builtin_amdgcn_s_setprio(0);
    BARRIER();

    // ---- phase 2: quadrant (0,1)
    LD_B(p, 1);
    STG_A(q, 1, t1);
    BARRIER();
    asm volatile("s_waitcnt lgkmcnt(0)" ::: "memory");
    __builtin_amdgcn_sched_barrier(0);
    __builtin_amdgcn_s_setprio(1); MFMA_Q(0, 1); __builtin_amdgcn_s_setprio(0);
    BARRIER();

    // ---- phase 3: quadrant (1,0)
    LD_A(p, 1);
    STG_B(p, 0, t2);
    BARRIER();
    asm volatile("s_waitcnt lgkmcnt(0)" ::: "memory");
    __builtin_amdgcn_sched_barrier(0);
    __builtin_amdgcn_s_setprio(1); MFMA_Q(1, 0); __builtin_amdgcn_s_setprio(0);
    BARRIER();

    // ---- phase 4: quadrant (1,1); counted vmcnt AFTER the MFMA cluster
    STG_B(p, 1, t2);
    BARRIER();
    __builtin_amdgcn_s_setprio(1); MFMA_Q(1, 1); __builtin_amdgcn_s_setprio(0);
    asm volatile("s_waitcnt vmcnt(4)" ::: "memory");
    BARRIER();
  }

  // C/D layout (m89-verified): col(n)=lane&15, row(m)=quad*4+reg
#pragma unroll
  for (int i = 0; i < 8; ++i) {
    const int mbase = m0 + wm * 128 + i * 16 + quad * 4;
#pragma unroll
    for (int j = 0; j < 4; ++j) {
      const int n = n0 + wn * 64 + j * 16 + lrow;
#pragma unroll
      for (int r = 0; r < 4; ++r)
        C[(size_t)(mbase + r) * N + n] = (bf16_t)acc[i][j][r];
    }
  }
#undef STG_A
#undef STG_B
#undef LD_A
#undef LD_B
#undef MFMA_Q
}

// ---------------- fused epilogue: WAVE-PER-ROW, fully vectorized (R4) -------
// 4 waves/block, one batch row per wave. Lane l owns four h-quads:
// h = c*256 + l*4 + k. Gate-interleaved IG/HG -> bf16x8 loads; params/cx/
// outputs all lane-contiguous float4. Reductions = 64-lane __shfl_xor.
// KNOWN-GOOD: 73.2 us, VGPR 108 (R5 measured). 1 row/wave is the register
// sweet spot — 2+ rows/wave needs >250 VGPR or a gate re-read (R8: both fatal).
__device__ inline float sigmoid_f(float x) { return 1.0f / (1.0f + __expf(-x)); }
__device__ inline float tanh_f(float x) {
  float e = __expf(2.0f * x);
  return 1.0f - 2.0f / (e + 1.0f);   // safe at +/-inf
}

__global__ __launch_bounds__(256) void ln_lstm_epi_wave2(
    const bf16_t* __restrict__ IG, const bf16_t* __restrict__ HG,
    const float* __restrict__ cx,
    const float* __restrict__ wi, const float* __restrict__ bi,
    const float* __restrict__ wh, const float* __restrict__ bh,
    const float* __restrict__ wc, const float* __restrict__ bc,
    float* __restrict__ hy_out, float* __restrict__ cy_out) {
  const int l = threadIdx.x & 63;
  const int b = blockIdx.x * 4 + (threadIdx.x >> 6);

  const bf16_t* igp = IG + (size_t)b * 4096;
  const bf16_t* hgp = HG + (size_t)b * 4096;

  bf16x8 igv[4][2], hgv[4][2];
  float4 cx4[4];
#pragma unroll
  for (int c = 0; c < 4; ++c) {
    const int n0 = c * 1024 + l * 16;
    igv[c][0] = *(const bf16x8*)(igp + n0);
    igv[c][1] = *(const bf16x8*)(igp + n0 + 8);
    hgv[c][0] = *(const bf16x8*)(hgp + n0);
    hgv[c][1] = *(const bf16x8*)(hgp + n0 + 8);
    cx4[c] = *(const float4*)(cx + (size_t)b * 1024 + c * 256 + l * 4);
  }

  float si = 0, qi = 0, sh = 0, qh = 0;
#pragma unroll
  for (int c = 0; c < 4; ++c)
#pragma unroll
    for (int hf = 0; hf < 2; ++hf)
#pragma unroll
      for (int e = 0; e < 8; ++e) {
        const float a = (float)igv[c][hf][e], d = (float)hgv[c][hf][e];
        si += a; qi = fmaf(a, a, qi);
        sh += d; qh = fmaf(d, d, qh);
      }
#pragma unroll
  for (int off = 1; off < 64; off <<= 1) {
    si += __shfl_xor(si, off); qi += __shfl_xor(qi, off);
    sh += __shfl_xor(sh, off); qh += __shfl_xor(qh, off);
  }
  const float invN = 1.0f / 4096.0f;
  const float mui = si * invN, muh = sh * invN;
  const float rsi = rsqrtf(fmaxf(qi * invN - mui * mui, 0.0f) + 1e-5f);
  const float rsh = rsqrtf(fmaxf(qh * invN - muh * muh, 0.0f) + 1e-5f);

  float cv[16], ov[16];
  float sc = 0, qc = 0;
#pragma unroll
  for (int c = 0; c < 4; ++c) {
    const int h0 = c * 256 + l * 4;
    float4 wiv[4], biv[4], whv[4], bhv[4];
#pragma unroll
    for (int g = 0; g < 4; ++g) {
      wiv[g] = *(const float4*)(wi + g * 1024 + h0);
      biv[g] = *(const float4*)(bi + g * 1024 + h0);
      whv[g] = *(const float4*)(wh + g * 1024 + h0);
      bhv[g] = *(const float4*)(bh + g * 1024 + h0);
    }
#pragma unroll
    for (int kk = 0; kk < 4; ++kk) {
      float G[4];
#pragma unroll
      for (int g = 0; g < 4; ++g) {
        const int idx = kk * 4 + g;
        const float gi = (float)igv[c][idx >> 3][idx & 7];
        const float gh = (float)hgv[c][idx >> 3][idx & 7];
        G[g] = (gi - mui) * rsi * ((const float*)&wiv[g])[kk] + ((const float*)&biv[g])[kk] +
               (gh - muh) * rsh * ((const float*)&whv[g])[kk] + ((const float*)&bhv[g])[kk];
      }
      const float in_g = sigmoid_f(G[0]);
      const float fo_g = sigmoid_f(G[1]);
      const float ce_g = tanh_f(G[2]);
      ov[c * 4 + kk] = sigmoid_f(G[3]);
      const float cc = fo_g * ((const float*)&cx4[c])[kk] + in_g * ce_g;
      cv[c * 4 + kk] = cc;
      sc += cc; qc = fmaf(cc, cc, qc);
    }
  }
#pragma unroll
  for (int off = 1; off < 64; off <<= 1) {
    sc += __shfl_xor(sc, off); qc += __shfl_xor(qc, off);
  }
  const float invH = 1.0f / 1024.0f;
  const float muc = sc * invH;
  const float rsc = rsqrtf(fmaxf(qc * invH - muc * muc, 0.0f) + 1e-5f);

#pragma unroll
  for (int c = 0; c < 4; ++c) {
    const int h0 = c * 256 + l * 4;
    const float4 wc4 = *(const float4*)(wc + h0);
    const float4 bc4 = *(const float4*)(bc + h0);
    float4 cyv, hyv;
#pragma unroll
    for (int kk = 0; kk < 4; ++kk) {
      const float cyn = (cv[c * 4 + kk] - muc) * rsc * ((const float*)&wc4)[kk] +
                        ((const float*)&bc4)[kk];
      ((float*)&cyv)[kk] = cyn;
      ((float*)&hyv)[kk] = ov[c * 4 + kk] * tanh_f(cyn);
    }
    *(float4*)(cy_out + (size_t)b * 1024 + h0) = cyv;
    *(float4*)(hy_out + (size_t)b * 1024 + h0) = hyv;
  }
}

extern "C" void kernel_launch(void* const* d_in, const int* in_sizes, int n_in,
                              void* d_out, int out_size, void* d_ws, size_t ws_size,
                              hipStream_t stream) {
  const float* input  = (const float*)d_in[0];
  const float* hx     = (const float*)d_in[1];
  const float* cx     = (const float*)d_in[2];
  const float* w_ih   = (const float*)d_in[3];
  const float* w_hh   = (const float*)d_in[4];
  const float* ln_i_w = (const float*)d_in[5];
  const float* ln_i_b = (const float*)d_in[6];
  const float* ln_h_w = (const float*)d_in[7];
  const float* ln_h_b = (const float*)d_in[8];
  const float* ln_c_w = (const float*)d_in[9];
  const float* ln_c_b = (const float*)d_in[10];

  float* out = (float*)d_out;
  float* hy = out;
  float* cy = out + (size_t)B_ * H_;

  // workspace (bf16): A 16MB | H 16MB | Wih 8MB | Whh 8MB | IG 64MB | HG 64MB
  bf16_t* Abf = (bf16_t*)d_ws;
  bf16_t* Hbf = Abf + (size_t)B_ * K_;
  bf16_t* Wib = Hbf + (size_t)B_ * K_;
  bf16_t* Whb = Wib + (size_t)G4 * K_;
  bf16_t* IG  = Whb + (size_t)G4 * K_;
  bf16_t* HG  = IG + (size_t)B_ * G4;

  prep_all2<<<4096, 256, 0, stream>>>(input, hx, w_ih, w_hh, Abf, Hbf, Wib, Whb);

  gemm_bt_dual8<<<dim3(16, 32, 2), 512, 0, stream>>>(Abf, Hbf, Wib, Whb, IG, HG);

  ln_lstm_epi_wave2<<<2048, 256, 0, stream>>>(IG, HG, cx, ln_i_w, ln_i_b,
                                              ln_h_w, ln_h_b, ln_c_w, ln_c_b, hy, cy);
}

// Round 10
// 365.322 us; speedup vs baseline: 1.2288x; 1.0263x over previous
//
#include <hip/hip_runtime.h>
#include <hip/hip_bf16.h>
#include <cstdint>
#include <cstddef>

typedef __bf16 bf16_t;
typedef bf16_t bf16x8 __attribute__((ext_vector_type(8)));
typedef float floatx4 __attribute__((ext_vector_type(4)));

static constexpr int B_ = 8192;   // batch
static constexpr int H_ = 1024;   // hidden
static constexpr int G4 = 4096;   // 4*H
static constexpr int K_ = 1024;   // input size == hidden size

// ---- async global->LDS, 16B per lane. HW semantics: lane's dest =
// WAVE-UNIFORM base + lane*16; global src is per-lane.
__device__ inline void async16(const void* g, void* l) {
  auto l3 = (__attribute__((address_space(3))) void*)(uint32_t)(uintptr_t)l;
  __builtin_amdgcn_global_load_lds(
      (__attribute__((address_space(1))) void*)(uintptr_t)g, l3, 16, 0, 0);
}

// ---------------- fused prep: casts + weight permute, ONE launch ------------
// blocks [0,2048):    input+hx fp32 -> bf16, 32 elems/thread (128B contig read)
// blocks [2048,4096): weight rows fp32 -> bf16 with gate-interleave perm,
//                     4 rows/block, 64 lanes x 16 elems per row
//                     (out row r' = h*4+g  <-  in row r = g*1024+h)
__global__ __launch_bounds__(256) void prep_all2(
    const float* __restrict__ input, const float* __restrict__ hx,
    const float* __restrict__ wih, const float* __restrict__ whh,
    bf16_t* __restrict__ Abf, bf16_t* __restrict__ Hbf,
    bf16_t* __restrict__ Wib, bf16_t* __restrict__ Whb) {
  const int bid = blockIdx.x;
  if (bid < 2048) {
    const int nt = B_ * K_ / 8;                 // 1M chunks per tensor
    const int c0 = (bid * 256 + threadIdx.x) * 4;  // first chunk [0, 2M)
    const float* src; bf16_t* dst; int idx;
    if (c0 < nt) { src = input; dst = Abf; idx = c0; }
    else         { src = hx;    dst = Hbf; idx = c0 - nt; }
    const float4* s4 = (const float4*)src + (size_t)idx * 2;
#pragma unroll
    for (int c = 0; c < 4; ++c) {
      const float4 v0 = s4[c * 2], v1 = s4[c * 2 + 1];
      bf16x8 o;
      o[0] = (bf16_t)v0.x; o[1] = (bf16_t)v0.y; o[2] = (bf16_t)v0.z; o[3] = (bf16_t)v0.w;
      o[4] = (bf16_t)v1.x; o[5] = (bf16_t)v1.y; o[6] = (bf16_t)v1.z; o[7] = (bf16_t)v1.w;
      ((bf16x8*)dst)[idx + c] = o;
    }
  } else {
    const int rb = (bid - 2048) * 4;            // first output row of block
    const int rr = rb + (threadIdx.x >> 6);     // global out row [0, 8192)
    const int rp = rr & 4095;                   // row within matrix
    const float* src = (rr < 4096) ? wih : whh;
    bf16_t*      dst = (rr < 4096) ? Wib : Whb;
    const int h = rp >> 2, g = rp & 3;
    const int rin = g * 1024 + h;
    const int c = (threadIdx.x & 63) * 16;
    const float4* s4 = (const float4*)(src + (size_t)rin * K_ + c);
    const float4 v0 = s4[0], v1 = s4[1], v2 = s4[2], v3 = s4[3];
    bf16x8 o0, o1;
    o0[0] = (bf16_t)v0.x; o0[1] = (bf16_t)v0.y; o0[2] = (bf16_t)v0.z; o0[3] = (bf16_t)v0.w;
    o0[4] = (bf16_t)v1.x; o0[5] = (bf16_t)v1.y; o0[6] = (bf16_t)v1.z; o0[7] = (bf16_t)v1.w;
    o1[0] = (bf16_t)v2.x; o1[1] = (bf16_t)v2.y; o1[2] = (bf16_t)v2.z; o1[3] = (bf16_t)v2.w;
    o1[4] = (bf16_t)v3.x; o1[5] = (bf16_t)v3.y; o1[6] = (bf16_t)v3.z; o1[7] = (bf16_t)v3.w;
    *(bf16x8*)(dst + (size_t)rp * K_ + c)     = o0;
    *(bf16x8*)(dst + (size_t)rp * K_ + c + 8) = o1;
  }
}

// ---------------- dual GEMM: C = A * W^T (both K-major), bf16 in/out --------
// R6 version (best stable: 140 us). 256x256 8-phase template, BK=64, 8 waves
// 2Mx4N, counted vmcnt(4), setprio, XOR-swizzled LDS (linear gload_lds dest
// + inverse-swizzled global src, rule #21), bijective XCD swizzle.
#define FENCE() asm volatile("" ::: "memory")
#define BARRIER() do { FENCE(); __builtin_amdgcn_s_barrier(); FENCE(); } while (0)

__global__ __launch_bounds__(512, 2) void gemm_bt_dual8(
    const bf16_t* __restrict__ A0, const bf16_t* __restrict__ A1,
    const bf16_t* __restrict__ W0, const bf16_t* __restrict__ W1,
    bf16_t* __restrict__ C0, bf16_t* __restrict__ C1) {
  constexpr int N = G4, K = K_, NT = K_ / 64;

  __shared__ bf16_t ldsA[2][16384];   // [buf][256 rows x 64 cols]
  __shared__ bf16_t ldsB[2][16384];

  // bijective XCD swizzle of flat block id (x fastest in dispatch order)
  const int flatb = blockIdx.x + (blockIdx.y << 4) + (blockIdx.z << 9);
  const int swzb  = (flatb & 7) * 128 + (flatb >> 3);
  const int bz = swzb >> 9;
  const int by = (swzb >> 4) & 31;
  const int bx = swzb & 15;

  const bf16_t* A = bz ? A1 : A0;
  const bf16_t* W = bz ? W1 : W0;
  bf16_t*       C = bz ? C1 : C0;

  const int tid  = threadIdx.x;
  const int lane = tid & 63;
  const int w    = tid >> 6;          // wave 0..7
  const int wm   = w >> 2, wn = w & 3;
  const int lrow = lane & 15, quad = lane >> 4;
  const int e    = lrow & 7;

  const int m0 = by * 256;
  const int n0 = bx * 256;

  // staging: thread t covers LDS 16B slot t of an 8KB sub-half (64 rows x 64
  // cols). row = t>>3, slot = t&7; global source chunk = slot ^ (row&7).
  const int srow   = tid >> 3;
  const int schunk = (tid & 7) ^ (srow & 7);
  const bf16_t* gA = A + (size_t)(m0 + srow) * K + schunk * 8;
  const bf16_t* gB = W + (size_t)(n0 + srow) * K + schunk * 8;
  const int wslot = w * 512;          // wave-uniform elem offset in sub-half

  // fragment read bases (elements), swizzled chunk = (ks*4+quad) ^ e
  const int aBase = (wm * 128 + lrow) * 64 + (quad ^ e) * 8;
  const int bBase = (wn * 64 + lrow) * 64 + (quad ^ e) * 8;

  floatx4 acc[8][4] = {};
  bf16x8 aF[4][2];
  bf16x8 bF[2][2][2];

#define STG_A(p, half, kt) do {                                          \
    bf16_t* _l = &ldsA[p][(half) * 8192 + wslot];                        \
    async16(gA + (size_t)((half) * 128) * K + (kt) * 64, _l);            \
    async16(gA + (size_t)((half) * 128 + 64) * K + (kt) * 64, _l + 4096); \
  } while (0)
#define STG_B(p, half, kt) do {                                          \
    bf16_t* _l = &ldsB[p][(half) * 8192 + wslot];                        \
    async16(gB + (size_t)((half) * 128) * K + (kt) * 64, _l);            \
    async16(gB + (size_t)((half) * 128 + 64) * K + (kt) * 64, _l + 4096); \
  } while (0)

#define LD_A(p, qm) do { _Pragma("unroll")                               \
    for (int i2 = 0; i2 < 4; ++i2) {                                     \
      const int o = aBase + (qm) * 4096 + i2 * 1024;                     \
      aF[i2][0] = *(const bf16x8*)&ldsA[p][o];                           \
      aF[i2][1] = *(const bf16x8*)&ldsA[p][o ^ 32];                      \
    } } while (0)
#define LD_B(p, qn) do { _Pragma("unroll")                               \
    for (int j2 = 0; j2 < 2; ++j2) {                                     \
      const int o = bBase + (qn) * 2048 + j2 * 1024;                     \
      bF[qn][j2][0] = *(const bf16x8*)&ldsB[p][o];                       \
      bF[qn][j2][1] = *(const bf16x8*)&ldsB[p][o ^ 32];                  \
    } } while (0)
#define MFMA_Q(qm, qn) do { _Pragma("unroll")                            \
    for (int i2 = 0; i2 < 4; ++i2) { _Pragma("unroll")                   \
      for (int j2 = 0; j2 < 2; ++j2) {                                   \
        floatx4& c = acc[(qm) * 4 + i2][(qn) * 2 + j2];                  \
        c = __builtin_amdgcn_mfma_f32_16x16x32_bf16(aF[i2][0], bF[qn][j2][0], c, 0, 0, 0); \
        c = __builtin_amdgcn_mfma_f32_16x16x32_bf16(aF[i2][1], bF[qn][j2][1], c, 0, 0, 0); \
      } } } while (0)

  // prologue: tile0 complete + tile1 B-halves; wait tile0 (leave tile1.B in flight)
  STG_B(0, 0, 0); STG_B(0, 1, 0);
  STG_A(0, 0, 0); STG_A(0, 1, 0);
  STG_B(1, 0, 1); STG_B(1, 1, 1);
  asm volatile("s_waitcnt vmcnt(4)" ::: "memory");
  BARRIER();

#pragma unroll 2
  for (int t = 0; t < NT; ++t) {
    const int p = t & 1, q = p ^ 1;
    const int t1 = (t + 1) & (NT - 1), t2 = (t + 2) & (NT - 1);

    // ---- phase 1: quadrant (0,0)
    LD_A(p, 0); LD_B(p, 0);
    STG_A(q, 0, t1);
    BARRIER();
    asm volatile("s_waitcnt lgkmcnt(0)" ::: "memory");
    __builtin_amdgcn_sched_barrier(0);
    __builtin_amdgcn_s_setprio(1); MFMA_Q(0, 0); __builtin_amdgcn_s_setprio(0);
    BARRIER();

    // ---- phase 2: quadrant (0,1)
    LD_B(p, 1);
    STG_A(q, 1, t1);
    BARRIER();
    asm volatile("s_waitcnt lgkmcnt(0)" ::: "memory");
    __builtin_amdgcn_sched_barrier(0);
    __builtin_amdgcn_s_setprio(1); MFMA_Q(0, 1); __builtin_amdgcn_s_setprio(0);
    BARRIER();

    // ---- phase 3: quadrant (1,0)
    LD_A(p, 1);
    STG_B(p, 0, t2);
    BARRIER();
    asm volatile("s_waitcnt lgkmcnt(0)" ::: "memory");
    __builtin_amdgcn_sched_barrier(0);
    __builtin_amdgcn_s_setprio(1); MFMA_Q(1, 0); __builtin_amdgcn_s_setprio(0);
    BARRIER();

    // ---- phase 4: quadrant (1,1); counted vmcnt AFTER the MFMA cluster
    STG_B(p, 1, t2);
    BARRIER();
    __builtin_amdgcn_s_setprio(1); MFMA_Q(1, 1); __builtin_amdgcn_s_setprio(0);
    asm volatile("s_waitcnt vmcnt(4)" ::: "memory");
    BARRIER();
  }

  // C/D layout (m89-verified): col(n)=lane&15, row(m)=quad*4+reg
#pragma unroll
  for (int i = 0; i < 8; ++i) {
    const int mbase = m0 + wm * 128 + i * 16 + quad * 4;
#pragma unroll
    for (int j = 0; j < 4; ++j) {
      const int n = n0 + wn * 64 + j * 16 + lrow;
#pragma unroll
      for (int r = 0; r < 4; ++r)
        C[(size_t)(mbase + r) * N + n] = (bf16_t)acc[i][j][r];
    }
  }
#undef STG_A
#undef STG_B
#undef LD_A
#undef LD_B
#undef MFMA_Q
}

// ---------------- fused epilogue: HALF-ROW PER WAVE -------------------------
// 4096 blocks x 4 waves; waves (2r, 2r+1) of a block share batch row
// b = blockIdx*2 + r, each handling 512 h (2 c-chunks). Latency theory (R5/R9
// counters): wave2 at VGPR 108 = 4 waves/SIMD was latency-bound (7 GB/s/CU,
// far under BW share). Halving per-wave state (gates 32 vs 64 VGPR) raises
// occupancy and halves every dependent phase; LN stats combine across the
// wave pair via a 16-float LDS slot + 2 __syncthreads.
__device__ inline float sigmoid_f(float x) { return 1.0f / (1.0f + __expf(-x)); }
__device__ inline float tanh_f(float x) {
  float e = __expf(2.0f * x);
  return 1.0f - 2.0f / (e + 1.0f);   // safe at +/-inf
}

__global__ __launch_bounds__(256) void ln_lstm_epi_half(
    const bf16_t* __restrict__ IG, const bf16_t* __restrict__ HG,
    const float* __restrict__ cx,
    const float* __restrict__ wi, const float* __restrict__ bi,
    const float* __restrict__ wh, const float* __restrict__ bh,
    const float* __restrict__ wc, const float* __restrict__ bc,
    float* __restrict__ hy_out, float* __restrict__ cy_out) {
  __shared__ float red1[2][2][4];   // [row][half][si,qi,sh,qh]
  __shared__ float red2[2][2][2];   // [row][half][sc,qc]

  const int tid = threadIdx.x;
  const int l  = tid & 63;
  const int w  = tid >> 6;          // wave 0..3
  const int rw = w >> 1;            // row within block
  const int j  = w & 1;             // half of row
  const int b  = blockIdx.x * 2 + rw;

  const bf16_t* igp = IG + (size_t)b * 4096 + j * 2048;
  const bf16_t* hgp = HG + (size_t)b * 4096 + j * 2048;

  bf16x8 igv[2][2], hgv[2][2];
  float4 cx4[2];
#pragma unroll
  for (int c = 0; c < 2; ++c) {
    const int n0 = c * 1024 + l * 16;
    igv[c][0] = *(const bf16x8*)(igp + n0);
    igv[c][1] = *(const bf16x8*)(igp + n0 + 8);
    hgv[c][0] = *(const bf16x8*)(hgp + n0);
    hgv[c][1] = *(const bf16x8*)(hgp + n0 + 8);
    cx4[c] = *(const float4*)(cx + (size_t)b * 1024 + j * 512 + c * 256 + l * 4);
  }

  // ---- partial gate-LN stats over this wave's 2048 elements
  float si = 0, qi = 0, sh = 0, qh = 0;
#pragma unroll
  for (int c = 0; c < 2; ++c)
#pragma unroll
    for (int hf = 0; hf < 2; ++hf)
#pragma unroll
      for (int e = 0; e < 8; ++e) {
        const float a = (float)igv[c][hf][e], d = (float)hgv[c][hf][e];
        si += a; qi = fmaf(a, a, qi);
        sh += d; qh = fmaf(d, d, qh);
      }
#pragma unroll
  for (int off = 1; off < 64; off <<= 1) {
    si += __shfl_xor(si, off); qi += __shfl_xor(qi, off);
    sh += __shfl_xor(sh, off); qh += __shfl_xor(qh, off);
  }
  if (l == 0) {
    red1[rw][j][0] = si; red1[rw][j][1] = qi;
    red1[rw][j][2] = sh; red1[rw][j][3] = qh;
  }
  __syncthreads();
  si = red1[rw][0][0] + red1[rw][1][0];
  qi = red1[rw][0][1] + red1[rw][1][1];
  sh = red1[rw][0][2] + red1[rw][1][2];
  qh = red1[rw][0][3] + red1[rw][1][3];

  const float invN = 1.0f / 4096.0f;
  const float mui = si * invN, muh = sh * invN;
  const float rsi = rsqrtf(fmaxf(qi * invN - mui * mui, 0.0f) + 1e-5f);
  const float rsh = rsqrtf(fmaxf(qh * invN - muh * muh, 0.0f) + 1e-5f);

  // ---- gates -> cell (params per c-chunk), partial c-LN stats
  float cv[8], ov[8];
  float sc = 0, qc = 0;
#pragma unroll
  for (int c = 0; c < 2; ++c) {
    const int h0 = j * 512 + c * 256 + l * 4;
    float4 wiv[4], biv[4], whv[4], bhv[4];
#pragma unroll
    for (int g = 0; g < 4; ++g) {
      wiv[g] = *(const float4*)(wi + g * 1024 + h0);
      biv[g] = *(const float4*)(bi + g * 1024 + h0);
      whv[g] = *(const float4*)(wh + g * 1024 + h0);
      bhv[g] = *(const float4*)(bh + g * 1024 + h0);
    }
#pragma unroll
    for (int kk = 0; kk < 4; ++kk) {
      float G[4];
#pragma unroll
      for (int g = 0; g < 4; ++g) {
        const int idx = kk * 4 + g;
        const float gi = (float)igv[c][idx >> 3][idx & 7];
        const float gh = (float)hgv[c][idx >> 3][idx & 7];
        G[g] = (gi - mui) * rsi * ((const float*)&wiv[g])[kk] + ((const float*)&biv[g])[kk] +
               (gh - muh) * rsh * ((const float*)&whv[g])[kk] + ((const float*)&bhv[g])[kk];
      }
      const float in_g = sigmoid_f(G[0]);
      const float fo_g = sigmoid_f(G[1]);
      const float ce_g = tanh_f(G[2]);
      ov[c * 4 + kk] = sigmoid_f(G[3]);
      const float cc = fo_g * ((const float*)&cx4[c])[kk] + in_g * ce_g;
      cv[c * 4 + kk] = cc;
      sc += cc; qc = fmaf(cc, cc, qc);
    }
  }
#pragma unroll
  for (int off = 1; off < 64; off <<= 1) {
    sc += __shfl_xor(sc, off); qc += __shfl_xor(qc, off);
  }
  if (l == 0) { red2[rw][j][0] = sc; red2[rw][j][1] = qc; }
  __syncthreads();
  sc = red2[rw][0][0] + red2[rw][1][0];
  qc = red2[rw][0][1] + red2[rw][1][1];

  const float invH = 1.0f / 1024.0f;
  const float muc = sc * invH;
  const float rsc = rsqrtf(fmaxf(qc * invH - muc * muc, 0.0f) + 1e-5f);

  // ---- c-LN + outputs
#pragma unroll
  for (int c = 0; c < 2; ++c) {
    const int h0 = j * 512 + c * 256 + l * 4;
    const float4 wc4 = *(const float4*)(wc + h0);
    const float4 bc4 = *(const float4*)(bc + h0);
    float4 cyv, hyv;
#pragma unroll
    for (int kk = 0; kk < 4; ++kk) {
      const float cyn = (cv[c * 4 + kk] - muc) * rsc * ((const float*)&wc4)[kk] +
                        ((const float*)&bc4)[kk];
      ((float*)&cyv)[kk] = cyn;
      ((float*)&hyv)[kk] = ov[c * 4 + kk] * tanh_f(cyn);
    }
    *(float4*)(cy_out + (size_t)b * 1024 + h0) = cyv;
    *(float4*)(hy_out + (size_t)b * 1024 + h0) = hyv;
  }
}

extern "C" void kernel_launch(void* const* d_in, const int* in_sizes, int n_in,
                              void* d_out, int out_size, void* d_ws, size_t ws_size,
                              hipStream_t stream) {
  const float* input  = (const float*)d_in[0];
  const float* hx     = (const float*)d_in[1];
  const float* cx     = (const float*)d_in[2];
  const float* w_ih   = (const float*)d_in[3];
  const float* w_hh   = (const float*)d_in[4];
  const float* ln_i_w = (const float*)d_in[5];
  const float* ln_i_b = (const float*)d_in[6];
  const float* ln_h_w = (const float*)d_in[7];
  const float* ln_h_b = (const float*)d_in[8];
  const float* ln_c_w = (const float*)d_in[9];
  const float* ln_c_b = (const float*)d_in[10];

  float* out = (float*)d_out;
  float* hy = out;
  float* cy = out + (size_t)B_ * H_;

  // workspace (bf16): A 16MB | H 16MB | Wih 8MB | Whh 8MB | IG 64MB | HG 64MB
  bf16_t* Abf = (bf16_t*)d_ws;
  bf16_t* Hbf = Abf + (size_t)B_ * K_;
  bf16_t* Wib = Hbf + (size_t)B_ * K_;
  bf16_t* Whb = Wib + (size_t)G4 * K_;
  bf16_t* IG  = Whb + (size_t)G4 * K_;
  bf16_t* HG  = IG + (size_t)B_ * G4;

  prep_all2<<<4096, 256, 0, stream>>>(input, hx, w_ih, w_hh, Abf, Hbf, Wib, Whb);

  gemm_bt_dual8<<<dim3(16, 32, 2), 512, 0, stream>>>(Abf, Hbf, Wib, Whb, IG, HG);

  ln_lstm_epi_half<<<4096, 256, 0, stream>>>(IG, HG, cx, ln_i_w, ln_i_b,
                                             ln_h_w, ln_h_b, ln_c_w, ln_c_b, hy, cy);
}

// Round 11
// 358.553 us; speedup vs baseline: 1.2520x; 1.0189x over previous
//
#include <hip/hip_runtime.h>
#include <hip/hip_bf16.h>
#include <cstdint>
#include <cstddef>

typedef __bf16 bf16_t;
typedef bf16_t bf16x8 __attribute__((ext_vector_type(8)));
typedef bf16_t bf16x4v __attribute__((ext_vector_type(4)));
typedef float floatx4 __attribute__((ext_vector_type(4)));

static constexpr int B_ = 8192;   // batch
static constexpr int H_ = 1024;   // hidden
static constexpr int G4 = 4096;   // 4*H
static constexpr int K_ = 1024;   // input size == hidden size

// ---- async global->LDS, 16B per lane. HW semantics: lane's dest =
// WAVE-UNIFORM base + lane*16; global src is per-lane.
__device__ inline void async16(const void* g, void* l) {
  auto l3 = (__attribute__((address_space(3))) void*)(uint32_t)(uintptr_t)l;
  __builtin_amdgcn_global_load_lds(
      (__attribute__((address_space(1))) void*)(uintptr_t)g, l3, 16, 0, 0);
}

// ---------------- fused prep: casts + weight permute, ONE launch ------------
// MEASURED-BEST version (R4: prep+gaps=142 vs 148/162 for coarser variants):
// 24576 fine-grained blocks schedule/ramp best for pure streaming.
// blocks [0,8192):    input+hx fp32 -> bf16, 8 elems/thread
// blocks [8192,24576): weight rows fp32 -> bf16 with gate-interleave perm
//                      (out row r' = h*4+g  <-  in row r = g*1024+h)
__global__ __launch_bounds__(256) void prep_all(
    const float* __restrict__ input, const float* __restrict__ hx,
    const float* __restrict__ wih, const float* __restrict__ whh,
    bf16_t* __restrict__ Abf, bf16_t* __restrict__ Hbf,
    bf16_t* __restrict__ Wib, bf16_t* __restrict__ Whb) {
  const int bid = blockIdx.x;
  if (bid < 8192) {
    const int n8 = B_ * K_ / 8;                 // 1M per tensor
    int gid = bid * 256 + threadIdx.x;          // [0, 2M)
    const float* src; bf16_t* dst; int idx;
    if (gid < n8) { src = input; dst = Abf; idx = gid; }
    else          { src = hx;    dst = Hbf; idx = gid - n8; }
    const float4 v0 = ((const float4*)src)[idx * 2];
    const float4 v1 = ((const float4*)src)[idx * 2 + 1];
    bf16x8 o;
    o[0] = (bf16_t)v0.x; o[1] = (bf16_t)v0.y; o[2] = (bf16_t)v0.z; o[3] = (bf16_t)v0.w;
    o[4] = (bf16_t)v1.x; o[5] = (bf16_t)v1.y; o[6] = (bf16_t)v1.z; o[7] = (bf16_t)v1.w;
    ((bf16x8*)dst)[idx] = o;
  } else {
    const int r = bid - 8192;                   // [0, 16384)
    const int rp = r & 4095;                    // output row within matrix
    const float* src = (r < 4096) ? wih : whh;
    bf16_t*      dst = (r < 4096) ? Wib : Whb;
    const int h = rp >> 2, g = rp & 3;
    const int rin = g * 1024 + h;
    const int c = threadIdx.x * 4;
    const float4 v = *(const float4*)(src + (size_t)rin * K_ + c);
    bf16x4v o;
    o[0] = (bf16_t)v.x; o[1] = (bf16_t)v.y; o[2] = (bf16_t)v.z; o[3] = (bf16_t)v.w;
    *(bf16x4v*)(dst + (size_t)rp * K_ + c) = o;
  }
}

// ---------------- dual GEMM: C = A * W^T (both K-major), bf16 in/out --------
// R6/R10 version (best stable: 137.6-141 us, WRITE exactly 128 MiB).
// 256x256 8-phase template, BK=64, 8 waves 2Mx4N, counted vmcnt(4), setprio,
// XOR-swizzled LDS (linear gload_lds dest + inverse-swizzled global src,
// rule #21), bijective XCD swizzle. At K=1024 (16 K-tiles) this sits at
// ~996 GF-equivalent / 43% MfmaUtil — the template's plateau for this shape
// (8 structural variants R0-R10 all landed 138-149).
#define FENCE() asm volatile("" ::: "memory")
#define BARRIER() do { FENCE(); __builtin_amdgcn_s_barrier(); FENCE(); } while (0)

__global__ __launch_bounds__(512, 2) void gemm_bt_dual8(
    const bf16_t* __restrict__ A0, const bf16_t* __restrict__ A1,
    const bf16_t* __restrict__ W0, const bf16_t* __restrict__ W1,
    bf16_t* __restrict__ C0, bf16_t* __restrict__ C1) {
  constexpr int N = G4, K = K_, NT = K_ / 64;

  __shared__ bf16_t ldsA[2][16384];   // [buf][256 rows x 64 cols]
  __shared__ bf16_t ldsB[2][16384];

  // bijective XCD swizzle of flat block id (x fastest in dispatch order)
  const int flatb = blockIdx.x + (blockIdx.y << 4) + (blockIdx.z << 9);
  const int swzb  = (flatb & 7) * 128 + (flatb >> 3);
  const int bz = swzb >> 9;
  const int by = (swzb >> 4) & 31;
  const int bx = swzb & 15;

  const bf16_t* A = bz ? A1 : A0;
  const bf16_t* W = bz ? W1 : W0;
  bf16_t*       C = bz ? C1 : C0;

  const int tid  = threadIdx.x;
  const int lane = tid & 63;
  const int w    = tid >> 6;          // wave 0..7
  const int wm   = w >> 2, wn = w & 3;
  const int lrow = lane & 15, quad = lane >> 4;
  const int e    = lrow & 7;

  const int m0 = by * 256;
  const int n0 = bx * 256;

  // staging: thread t covers LDS 16B slot t of an 8KB sub-half (64 rows x 64
  // cols). row = t>>3, slot = t&7; global source chunk = slot ^ (row&7).
  const int srow   = tid >> 3;
  const int schunk = (tid & 7) ^ (srow & 7);
  const bf16_t* gA = A + (size_t)(m0 + srow) * K + schunk * 8;
  const bf16_t* gB = W + (size_t)(n0 + srow) * K + schunk * 8;
  const int wslot = w * 512;          // wave-uniform elem offset in sub-half

  // fragment read bases (elements), swizzled chunk = (ks*4+quad) ^ e
  const int aBase = (wm * 128 + lrow) * 64 + (quad ^ e) * 8;
  const int bBase = (wn * 64 + lrow) * 64 + (quad ^ e) * 8;

  floatx4 acc[8][4] = {};
  bf16x8 aF[4][2];
  bf16x8 bF[2][2][2];

#define STG_A(p, half, kt) do {                                          \
    bf16_t* _l = &ldsA[p][(half) * 8192 + wslot];                        \
    async16(gA + (size_t)((half) * 128) * K + (kt) * 64, _l);            \
    async16(gA + (size_t)((half) * 128 + 64) * K + (kt) * 64, _l + 4096); \
  } while (0)
#define STG_B(p, half, kt) do {                                          \
    bf16_t* _l = &ldsB[p][(half) * 8192 + wslot];                        \
    async16(gB + (size_t)((half) * 128) * K + (kt) * 64, _l);            \
    async16(gB + (size_t)((half) * 128 + 64) * K + (kt) * 64, _l + 4096); \
  } while (0)

#define LD_A(p, qm) do { _Pragma("unroll")                               \
    for (int i2 = 0; i2 < 4; ++i2) {                                     \
      const int o = aBase + (qm) * 4096 + i2 * 1024;                     \
      aF[i2][0] = *(const bf16x8*)&ldsA[p][o];                           \
      aF[i2][1] = *(const bf16x8*)&ldsA[p][o ^ 32];                      \
    } } while (0)
#define LD_B(p, qn) do { _Pragma("unroll")                               \
    for (int j2 = 0; j2 < 2; ++j2) {                                     \
      const int o = bBase + (qn) * 2048 + j2 * 1024;                     \
      bF[qn][j2][0] = *(const bf16x8*)&ldsB[p][o];                       \
      bF[qn][j2][1] = *(const bf16x8*)&ldsB[p][o ^ 32];                  \
    } } while (0)
#define MFMA_Q(qm, qn) do { _Pragma("unroll")                            \
    for (int i2 = 0; i2 < 4; ++i2) { _Pragma("unroll")                   \
      for (int j2 = 0; j2 < 2; ++j2) {                                   \
        floatx4& c = acc[(qm) * 4 + i2][(qn) * 2 + j2];                  \
        c = __builtin_amdgcn_mfma_f32_16x16x32_bf16(aF[i2][0], bF[qn][j2][0], c, 0, 0, 0); \
        c = __builtin_amdgcn_mfma_f32_16x16x32_bf16(aF[i2][1], bF[qn][j2][1], c, 0, 0, 0); \
      } } } while (0)

  // prologue: tile0 complete + tile1 B-halves; wait tile0 (leave tile1.B in flight)
  STG_B(0, 0, 0); STG_B(0, 1, 0);
  STG_A(0, 0, 0); STG_A(0, 1, 0);
  STG_B(1, 0, 1); STG_B(1, 1, 1);
  asm volatile("s_waitcnt vmcnt(4)" ::: "memory");
  BARRIER();

#pragma unroll 2
  for (int t = 0; t < NT; ++t) {
    const int p = t & 1, q = p ^ 1;
    const int t1 = (t + 1) & (NT - 1), t2 = (t + 2) & (NT - 1);

    // ---- phase 1: quadrant (0,0)
    LD_A(p, 0); LD_B(p, 0);
    STG_A(q, 0, t1);
    BARRIER();
    asm volatile("s_waitcnt lgkmcnt(0)" ::: "memory");
    __builtin_amdgcn_sched_barrier(0);
    __builtin_amdgcn_s_setprio(1); MFMA_Q(0, 0); __builtin_amdgcn_s_setprio(0);
    BARRIER();

    // ---- phase 2: quadrant (0,1)
    LD_B(p, 1);
    STG_A(q, 1, t1);
    BARRIER();
    asm volatile("s_waitcnt lgkmcnt(0)" ::: "memory");
    __builtin_amdgcn_sched_barrier(0);
    __builtin_amdgcn_s_setprio(1); MFMA_Q(0, 1); __builtin_amdgcn_s_setprio(0);
    BARRIER();

    // ---- phase 3: quadrant (1,0)
    LD_A(p, 1);
    STG_B(p, 0, t2);
    BARRIER();
    asm volatile("s_waitcnt lgkmcnt(0)" ::: "memory");
    __builtin_amdgcn_sched_barrier(0);
    __builtin_amdgcn_s_setprio(1); MFMA_Q(1, 0); __builtin_amdgcn_s_setprio(0);
    BARRIER();

    // ---- phase 4: quadrant (1,1); counted vmcnt AFTER the MFMA cluster
    STG_B(p, 1, t2);
    BARRIER();
    __builtin_amdgcn_s_setprio(1); MFMA_Q(1, 1); __builtin_amdgcn_s_setprio(0);
    asm volatile("s_waitcnt vmcnt(4)" ::: "memory");
    BARRIER();
  }

  // C/D layout (m89-verified): col(n)=lane&15, row(m)=quad*4+reg
#pragma unroll
  for (int i = 0; i < 8; ++i) {
    const int mbase = m0 + wm * 128 + i * 16 + quad * 4;
#pragma unroll
    for (int j = 0; j < 4; ++j) {
      const int n = n0 + wn * 64 + j * 16 + lrow;
#pragma unroll
      for (int r = 0; r < 4; ++r)
        C[(size_t)(mbase + r) * N + n] = (bf16_t)acc[i][j][r];
    }
  }
#undef STG_A
#undef STG_B
#undef LD_A
#undef LD_B
#undef MFMA_Q
}

// ---------------- fused epilogue: HALF-ROW PER WAVE (R10, best epi) ---------
// 4096 blocks x 4 waves; waves (2r, 2r+1) share batch row b = blockIdx*2 + r,
// each handling 512 h (2 c-chunks). Halved per-wave state raises occupancy
// and halves every dependent phase; LN stats combine across the wave pair
// via a small LDS slot + 2 __syncthreads. (R10: ~7us faster than wave2.)
__device__ inline float sigmoid_f(float x) { return 1.0f / (1.0f + __expf(-x)); }
__device__ inline float tanh_f(float x) {
  float e = __expf(2.0f * x);
  return 1.0f - 2.0f / (e + 1.0f);   // safe at +/-inf
}

__global__ __launch_bounds__(256) void ln_lstm_epi_half(
    const bf16_t* __restrict__ IG, const bf16_t* __restrict__ HG,
    const float* __restrict__ cx,
    const float* __restrict__ wi, const float* __restrict__ bi,
    const float* __restrict__ wh, const float* __restrict__ bh,
    const float* __restrict__ wc, const float* __restrict__ bc,
    float* __restrict__ hy_out, float* __restrict__ cy_out) {
  __shared__ float red1[2][2][4];   // [row][half][si,qi,sh,qh]
  __shared__ float red2[2][2][2];   // [row][half][sc,qc]

  const int tid = threadIdx.x;
  const int l  = tid & 63;
  const int w  = tid >> 6;          // wave 0..3
  const int rw = w >> 1;            // row within block
  const int j  = w & 1;             // half of row
  const int b  = blockIdx.x * 2 + rw;

  const bf16_t* igp = IG + (size_t)b * 4096 + j * 2048;
  const bf16_t* hgp = HG + (size_t)b * 4096 + j * 2048;

  bf16x8 igv[2][2], hgv[2][2];
  float4 cx4[2];
#pragma unroll
  for (int c = 0; c < 2; ++c) {
    const int n0 = c * 1024 + l * 16;
    igv[c][0] = *(const bf16x8*)(igp + n0);
    igv[c][1] = *(const bf16x8*)(igp + n0 + 8);
    hgv[c][0] = *(const bf16x8*)(hgp + n0);
    hgv[c][1] = *(const bf16x8*)(hgp + n0 + 8);
    cx4[c] = *(const float4*)(cx + (size_t)b * 1024 + j * 512 + c * 256 + l * 4);
  }

  // ---- partial gate-LN stats over this wave's 2048 elements
  float si = 0, qi = 0, sh = 0, qh = 0;
#pragma unroll
  for (int c = 0; c < 2; ++c)
#pragma unroll
    for (int hf = 0; hf < 2; ++hf)
#pragma unroll
      for (int e = 0; e < 8; ++e) {
        const float a = (float)igv[c][hf][e], d = (float)hgv[c][hf][e];
        si += a; qi = fmaf(a, a, qi);
        sh += d; qh = fmaf(d, d, qh);
      }
#pragma unroll
  for (int off = 1; off < 64; off <<= 1) {
    si += __shfl_xor(si, off); qi += __shfl_xor(qi, off);
    sh += __shfl_xor(sh, off); qh += __shfl_xor(qh, off);
  }
  if (l == 0) {
    red1[rw][j][0] = si; red1[rw][j][1] = qi;
    red1[rw][j][2] = sh; red1[rw][j][3] = qh;
  }
  __syncthreads();
  si = red1[rw][0][0] + red1[rw][1][0];
  qi = red1[rw][0][1] + red1[rw][1][1];
  sh = red1[rw][0][2] + red1[rw][1][2];
  qh = red1[rw][0][3] + red1[rw][1][3];

  const float invN = 1.0f / 4096.0f;
  const float mui = si * invN, muh = sh * invN;
  const float rsi = rsqrtf(fmaxf(qi * invN - mui * mui, 0.0f) + 1e-5f);
  const float rsh = rsqrtf(fmaxf(qh * invN - muh * muh, 0.0f) + 1e-5f);

  // ---- gates -> cell (params per c-chunk), partial c-LN stats
  float cv[8], ov[8];
  float sc = 0, qc = 0;
#pragma unroll
  for (int c = 0; c < 2; ++c) {
    const int h0 = j * 512 + c * 256 + l * 4;
    float4 wiv[4], biv[4], whv[4], bhv[4];
#pragma unroll
    for (int g = 0; g < 4; ++g) {
      wiv[g] = *(const float4*)(wi + g * 1024 + h0);
      biv[g] = *(const float4*)(bi + g * 1024 + h0);
      whv[g] = *(const float4*)(wh + g * 1024 + h0);
      bhv[g] = *(const float4*)(bh + g * 1024 + h0);
    }
#pragma unroll
    for (int kk = 0; kk < 4; ++kk) {
      float G[4];
#pragma unroll
      for (int g = 0; g < 4; ++g) {
        const int idx = kk * 4 + g;
        const float gi = (float)igv[c][idx >> 3][idx & 7];
        const float gh = (float)hgv[c][idx >> 3][idx & 7];
        G[g] = (gi - mui) * rsi * ((const float*)&wiv[g])[kk] + ((const float*)&biv[g])[kk] +
               (gh - muh) * rsh * ((const float*)&whv[g])[kk] + ((const float*)&bhv[g])[kk];
      }
      const float in_g = sigmoid_f(G[0]);
      const float fo_g = sigmoid_f(G[1]);
      const float ce_g = tanh_f(G[2]);
      ov[c * 4 + kk] = sigmoid_f(G[3]);
      const float cc = fo_g * ((const float*)&cx4[c])[kk] + in_g * ce_g;
      cv[c * 4 + kk] = cc;
      sc += cc; qc = fmaf(cc, cc, qc);
    }
  }
#pragma unroll
  for (int off = 1; off < 64; off <<= 1) {
    sc += __shfl_xor(sc, off); qc += __shfl_xor(qc, off);
  }
  if (l == 0) { red2[rw][j][0] = sc; red2[rw][j][1] = qc; }
  __syncthreads();
  sc = red2[rw][0][0] + red2[rw][1][0];
  qc = red2[rw][0][1] + red2[rw][1][1];

  const float invH = 1.0f / 1024.0f;
  const float muc = sc * invH;
  const float rsc = rsqrtf(fmaxf(qc * invH - muc * muc, 0.0f) + 1e-5f);

  // ---- c-LN + outputs
#pragma unroll
  for (int c = 0; c < 2; ++c) {
    const int h0 = j * 512 + c * 256 + l * 4;
    const float4 wc4 = *(const float4*)(wc + h0);
    const float4 bc4 = *(const float4*)(bc + h0);
    float4 cyv, hyv;
#pragma unroll
    for (int kk = 0; kk < 4; ++kk) {
      const float cyn = (cv[c * 4 + kk] - muc) * rsc * ((const float*)&wc4)[kk] +
                        ((const float*)&bc4)[kk];
      ((float*)&cyv)[kk] = cyn;
      ((float*)&hyv)[kk] = ov[c * 4 + kk] * tanh_f(cyn);
    }
    *(float4*)(cy_out + (size_t)b * 1024 + h0) = cyv;
    *(float4*)(hy_out + (size_t)b * 1024 + h0) = hyv;
  }
}

extern "C" void kernel_launch(void* const* d_in, const int* in_sizes, int n_in,
                              void* d_out, int out_size, void* d_ws, size_t ws_size,
                              hipStream_t stream) {
  const float* input  = (const float*)d_in[0];
  const float* hx     = (const float*)d_in[1];
  const float* cx     = (const float*)d_in[2];
  const float* w_ih   = (const float*)d_in[3];
  const float* w_hh   = (const float*)d_in[4];
  const float* ln_i_w = (const float*)d_in[5];
  const float* ln_i_b = (const float*)d_in[6];
  const float* ln_h_w = (const float*)d_in[7];
  const float* ln_h_b = (const float*)d_in[8];
  const float* ln_c_w = (const float*)d_in[9];
  const float* ln_c_b = (const float*)d_in[10];

  float* out = (float*)d_out;
  float* hy = out;
  float* cy = out + (size_t)B_ * H_;

  // workspace (bf16): A 16MB | H 16MB | Wih 8MB | Whh 8MB | IG 64MB | HG 64MB
  bf16_t* Abf = (bf16_t*)d_ws;
  bf16_t* Hbf = Abf + (size_t)B_ * K_;
  bf16_t* Wib = Hbf + (size_t)B_ * K_;
  bf16_t* Whb = Wib + (size_t)G4 * K_;
  bf16_t* IG  = Whb + (size_t)G4 * K_;
  bf16_t* HG  = IG + (size_t)B_ * G4;

  prep_all<<<24576, 256, 0, stream>>>(input, hx, w_ih, w_hh, Abf, Hbf, Wib, Whb);

  gemm_bt_dual8<<<dim3(16, 32, 2), 512, 0, stream>>>(Abf, Hbf, Wib, Whb, IG, HG);

  ln_lstm_epi_half<<<4096, 256, 0, stream>>>(IG, HG, cx, ln_i_w, ln_i_b,
                                             ln_h_w, ln_h_b, ln_c_w, ln_c_b, hy, cy);
}